// Round 2
// baseline (1666.044 us; speedup 1.0000x reference)
//
#include <hip/hip_runtime.h>

// =====================================================================
// All I/O is float32 (per reference dtypes; npz sizes confirm).
//
// Kernel 1: fused QKV + windowed attention (one block per window*head).
//   grid = 1024 windows * 8 heads = 8192 blocks, 256 threads.
//   X tile staged fp32 in two K=128 chunks; QKV accumulated in regs.
//   Writes attn output (token-major (65536,256), channel = head*32+ch)
//   into d_out; kernel 2 projects in place.
//   LDS: sXf 33792 B (aliased by sS 16896 B after QKV), sQKV 27648 B,
//        sPE 900 B -> 62340 B total.
// =====================================================================
__global__ __launch_bounds__(256, 2)
void winattn_kernel(const float* __restrict__ x,
                    const float* __restrict__ w_qkv,
                    const float* __restrict__ pe,
                    float* __restrict__ attn_out)
{
    __shared__ __align__(16) float sXf[64][132];       // X chunk, pad to 132
    __shared__ __align__(16) float sQKV[3][64][36];    // Q,K,V fp32, pad to 36
    __shared__ float sPE[225];

    // S/P buffer aliases the X-chunk tile (dead after QKV phase)
    float (*sS)[66] = reinterpret_cast<float(*)[66]>(&sXf[0][0]);

    const int tid = threadIdx.x;
    const int h   = blockIdx.x & 7;       // head
    const int wid = blockIdx.x >> 3;      // window 0..1023
    const int blw = wid >> 6;             // b*l  0..15
    const int whr = (wid >> 3) & 7;       // window row
    const int wwc = wid & 7;              // window col
    const int tok_base = blw * 4096 + whr * 512 + wwc * 8;
    // token(i) = tok_base + (i>>3)*64 + (i&7)

    if (tid < 225) sPE[tid] = pe[tid];

    const int qi = tid >> 2;              // row 0..63
    const int qc = (tid & 3) << 3;        // channel block 0,8,16,24

    float acc[3][8];
    #pragma unroll
    for (int m = 0; m < 3; ++m)
        #pragma unroll
        for (int c = 0; c < 8; ++c) acc[m][c] = 0.f;

    #pragma unroll
    for (int kc = 0; kc < 2; ++kc) {
        // ---- stage X chunk (64 rows x 128 floats), coalesced 16B ----
        #pragma unroll
        for (int it = 0; it < 8; ++it) {
            int g  = tid + it * 256;          // 0..2047 float4 slots
            int i  = g >> 5;                  // row
            int c4 = (g & 31) << 2;           // float col 0..124
            int tok = tok_base + ((i >> 3) << 6) + (i & 7);
            float4 v = *reinterpret_cast<const float4*>(
                x + (size_t)tok * 256 + kc * 128 + c4);
            *reinterpret_cast<float4*>(&sXf[i][c4]) = v;
        }
        __syncthreads();

        // ---- accumulate QKV partials over this chunk ----
        for (int kk = 0; kk < 128; kk += 4) {
            float4 xv = *reinterpret_cast<const float4*>(&sXf[qi][kk]);
            float xf[4] = {xv.x, xv.y, xv.z, xv.w};
            #pragma unroll
            for (int j = 0; j < 4; ++j) {
                const float* wr = w_qkv + (size_t)(kc * 128 + kk + j) * 768
                                  + h * 32 + qc;
                #pragma unroll
                for (int m = 0; m < 3; ++m) {
                    float4 w0 = *reinterpret_cast<const float4*>(wr + m * 256);
                    float4 w1 = *reinterpret_cast<const float4*>(wr + m * 256 + 4);
                    acc[m][0] = fmaf(xf[j], w0.x, acc[m][0]);
                    acc[m][1] = fmaf(xf[j], w0.y, acc[m][1]);
                    acc[m][2] = fmaf(xf[j], w0.z, acc[m][2]);
                    acc[m][3] = fmaf(xf[j], w0.w, acc[m][3]);
                    acc[m][4] = fmaf(xf[j], w1.x, acc[m][4]);
                    acc[m][5] = fmaf(xf[j], w1.y, acc[m][5]);
                    acc[m][6] = fmaf(xf[j], w1.z, acc[m][6]);
                    acc[m][7] = fmaf(xf[j], w1.w, acc[m][7]);
                }
            }
        }
        __syncthreads();   // all reads of sXf chunk done before restage/alias
    }

    // ---- publish QKV to LDS ----
    #pragma unroll
    for (int m = 0; m < 3; ++m) {
        *reinterpret_cast<float4*>(&sQKV[m][qi][qc]) =
            make_float4(acc[m][0], acc[m][1], acc[m][2], acc[m][3]);
        *reinterpret_cast<float4*>(&sQKV[m][qi][qc + 4]) =
            make_float4(acc[m][4], acc[m][5], acc[m][6], acc[m][7]);
    }
    __syncthreads();

    // ---- S = Q K^T * scale + bias; softmax in registers ----
    const int si   = tid >> 2;            // query row
    const int jsel = tid & 3;             // key-column slice (j = 4*jj+jsel)
    float qrow[32];
    #pragma unroll
    for (int k4 = 0; k4 < 32; k4 += 4) {
        float4 qv = *reinterpret_cast<const float4*>(&sQKV[0][si][k4]);
        qrow[k4 + 0] = qv.x; qrow[k4 + 1] = qv.y;
        qrow[k4 + 2] = qv.z; qrow[k4 + 3] = qv.w;
    }
    const int irow = si >> 3, icol = si & 7;
    float sv[16];
    float mx = -3.0e38f;
    #pragma unroll
    for (int jj = 0; jj < 16; ++jj) {
        int j = (jj << 2) + jsel;
        float d = 0.f;
        #pragma unroll
        for (int k4 = 0; k4 < 32; k4 += 4) {
            float4 kv = *reinterpret_cast<const float4*>(&sQKV[1][j][k4]);
            d = fmaf(qrow[k4 + 0], kv.x, d);
            d = fmaf(qrow[k4 + 1], kv.y, d);
            d = fmaf(qrow[k4 + 2], kv.z, d);
            d = fmaf(qrow[k4 + 3], kv.w, d);
        }
        int dy = (j >> 3) - irow + 7;
        int dx = (j & 7)  - icol + 7;
        float s = d * 0.17677669529663687f + sPE[dy * 15 + dx];
        sv[jj] = s;
        mx = fmaxf(mx, s);
    }
    mx = fmaxf(mx, __shfl_xor(mx, 1, 64));
    mx = fmaxf(mx, __shfl_xor(mx, 2, 64));
    float sum = 0.f;
    #pragma unroll
    for (int jj = 0; jj < 16; ++jj) { sv[jj] = __expf(sv[jj] - mx); sum += sv[jj]; }
    sum += __shfl_xor(sum, 1, 64);
    sum += __shfl_xor(sum, 2, 64);
    const float inv = 1.0f / sum;
    #pragma unroll
    for (int jj = 0; jj < 16; ++jj)
        sS[si][(jj << 2) + jsel] = sv[jj] * inv;
    __syncthreads();

    // ---- O = P V ; write fp32 to attn_out ----
    const int oc = (tid & 3) << 3;        // output channel block
    float oacc[8];
    #pragma unroll
    for (int c = 0; c < 8; ++c) oacc[c] = 0.f;
    #pragma unroll 8
    for (int j = 0; j < 64; ++j) {
        float p = sS[si][j];
        float4 v0 = *reinterpret_cast<const float4*>(&sQKV[2][j][oc]);
        float4 v1 = *reinterpret_cast<const float4*>(&sQKV[2][j][oc + 4]);
        oacc[0] = fmaf(p, v0.x, oacc[0]);
        oacc[1] = fmaf(p, v0.y, oacc[1]);
        oacc[2] = fmaf(p, v0.z, oacc[2]);
        oacc[3] = fmaf(p, v0.w, oacc[3]);
        oacc[4] = fmaf(p, v1.x, oacc[4]);
        oacc[5] = fmaf(p, v1.y, oacc[5]);
        oacc[6] = fmaf(p, v1.z, oacc[6]);
        oacc[7] = fmaf(p, v1.w, oacc[7]);
    }
    int tok = tok_base + ((si >> 3) << 6) + (si & 7);
    float* dst = attn_out + (size_t)tok * 256 + h * 32 + oc;
    *reinterpret_cast<float4*>(dst) =
        make_float4(oacc[0], oacc[1], oacc[2], oacc[3]);
    *reinterpret_cast<float4*>(dst + 4) =
        make_float4(oacc[4], oacc[5], oacc[6], oacc[7]);
}

// =====================================================================
// Kernel 2: in-place output projection out = A @ w_out + b_out (fp32).
// Each block owns 64 full rows; A staged in two K=128 chunks, partials
// accumulated in regs, rows overwritten only after both chunks consumed.
// grid = 1024 blocks, 256 threads; thread tile = 4 rows x 16 cols.
// =====================================================================
__global__ __launch_bounds__(256, 2)
void proj_kernel(float* __restrict__ io,
                 const float* __restrict__ w_out,
                 const float* __restrict__ b_out)
{
    __shared__ __align__(16) float sA[64][132];
    const int tid = threadIdx.x;
    const size_t m0 = (size_t)blockIdx.x * 64;
    const int ig = tid >> 4;              // 0..15 -> rows ig*4..ig*4+3
    const int cb = (tid & 15) << 4;       // cols cb..cb+15

    float acc[4][16];
    #pragma unroll
    for (int di = 0; di < 4; ++di)
        #pragma unroll
        for (int c = 0; c < 16; ++c) acc[di][c] = 0.f;

    #pragma unroll
    for (int kc = 0; kc < 2; ++kc) {
        #pragma unroll
        for (int it = 0; it < 8; ++it) {
            int g  = tid + it * 256;
            int i  = g >> 5;
            int c4 = (g & 31) << 2;
            float4 v = *reinterpret_cast<const float4*>(
                io + (m0 + i) * 256 + kc * 128 + c4);
            *reinterpret_cast<float4*>(&sA[i][c4]) = v;
        }
        __syncthreads();

        for (int kk = 0; kk < 128; kk += 4) {
            float4 a0 = *reinterpret_cast<const float4*>(&sA[ig * 4 + 0][kk]);
            float4 a1 = *reinterpret_cast<const float4*>(&sA[ig * 4 + 1][kk]);
            float4 a2 = *reinterpret_cast<const float4*>(&sA[ig * 4 + 2][kk]);
            float4 a3 = *reinterpret_cast<const float4*>(&sA[ig * 4 + 3][kk]);
            float ar[4][4] = {{a0.x, a0.y, a0.z, a0.w},
                              {a1.x, a1.y, a1.z, a1.w},
                              {a2.x, a2.y, a2.z, a2.w},
                              {a3.x, a3.y, a3.z, a3.w}};
            #pragma unroll
            for (int j = 0; j < 4; ++j) {
                const float* wr = w_out + (size_t)(kc * 128 + kk + j) * 256 + cb;
                float4 w0 = *reinterpret_cast<const float4*>(wr);
                float4 w1 = *reinterpret_cast<const float4*>(wr + 4);
                float4 w2 = *reinterpret_cast<const float4*>(wr + 8);
                float4 w3 = *reinterpret_cast<const float4*>(wr + 12);
                float wf[16] = {w0.x, w0.y, w0.z, w0.w, w1.x, w1.y, w1.z, w1.w,
                                w2.x, w2.y, w2.z, w2.w, w3.x, w3.y, w3.z, w3.w};
                #pragma unroll
                for (int di = 0; di < 4; ++di) {
                    float a = ar[di][j];
                    #pragma unroll
                    for (int c = 0; c < 16; ++c)
                        acc[di][c] = fmaf(a, wf[c], acc[di][c]);
                }
            }
        }
        __syncthreads();
    }

    float bias[16];
    #pragma unroll
    for (int c = 0; c < 16; ++c) bias[c] = b_out[cb + c];

    #pragma unroll
    for (int di = 0; di < 4; ++di) {
        float o[16];
        #pragma unroll
        for (int c = 0; c < 16; ++c) o[c] = acc[di][c] + bias[c];
        float* dst = io + (m0 + ig * 4 + di) * 256 + cb;
        *reinterpret_cast<float4*>(dst)      = make_float4(o[0],  o[1],  o[2],  o[3]);
        *reinterpret_cast<float4*>(dst + 4)  = make_float4(o[4],  o[5],  o[6],  o[7]);
        *reinterpret_cast<float4*>(dst + 8)  = make_float4(o[8],  o[9],  o[10], o[11]);
        *reinterpret_cast<float4*>(dst + 12) = make_float4(o[12], o[13], o[14], o[15]);
    }
}

extern "C" void kernel_launch(void* const* d_in, const int* in_sizes, int n_in,
                              void* d_out, int out_size, void* d_ws, size_t ws_size,
                              hipStream_t stream) {
    const float* x     = (const float*)d_in[0];  // (2,8,64,64,256) f32
    const float* w_qkv = (const float*)d_in[1];  // (256,768) f32
    const float* w_out = (const float*)d_in[2];  // (256,256) f32
    const float* b_out = (const float*)d_in[3];  // (256,) f32
    const float* pe    = (const float*)d_in[4];  // (15,15) f32
    (void)in_sizes; (void)n_in; (void)d_ws; (void)ws_size; (void)out_size;

    float* out = (float*)d_out;                  // (65536,256) f32

    winattn_kernel<<<dim3(8192), dim3(256), 0, stream>>>(x, w_qkv, pe, out);
    proj_kernel   <<<dim3(1024), dim3(256), 0, stream>>>(out, w_out, b_out);
}

// Round 3
// 210.722 us; speedup vs baseline: 7.9064x; 7.9064x over previous
//
#include <hip/hip_runtime.h>

typedef float f32x4 __attribute__((ext_vector_type(4)));
typedef short bf16x8 __attribute__((ext_vector_type(8)));

// ---------- helpers ----------
__device__ __forceinline__ unsigned short f2bf(float f) {
    union { float f; unsigned int i; } x;
    x.f = f;
    unsigned int i = x.i;
    unsigned int lsb = (i >> 16) & 1u;
    i += 0x7FFFu + lsb;                   // RNE (inputs finite)
    return (unsigned short)(i >> 16);
}
__device__ __forceinline__ bf16x8 ldsFrag(const unsigned short* p) {
    return *reinterpret_cast<const bf16x8*>(p);
}

// =====================================================================
// Kernel 1: fused QKV (MFMA) + windowed attention (MFMA).
// grid = 8192 (1024 windows x 8 heads), 256 threads = 4 waves.
// wave w owns token rows 16w..16w+15 (QKV m-tile) and the same 16
// queries in the attention phase.
// LDS 63,364 B -> 2 blocks/CU.
// =====================================================================
__global__ __launch_bounds__(256, 2)
void winattn_kernel(const float* __restrict__ x,
                    const float* __restrict__ w_qkv,
                    const float* __restrict__ pe,
                    float* __restrict__ attn_out)
{
    __shared__ __align__(16) unsigned short sX[64][264];  // X bf16 (row 528 B)
    __shared__ __align__(16) unsigned short sW[96][72];   // W^T chunk (n-major, K=64)
    __shared__ __align__(16) unsigned short sQ[64][40];   // Q bf16 [tok][ch32]
    __shared__ __align__(16) unsigned short sK[64][40];   // K bf16 [tok][ch32]
    __shared__ __align__(16) unsigned short sVT[32][72];  // V^T bf16 [ch][tok64]
    __shared__ float sPE[225];

    // P buffers alias sX (dead after QKV GEMM): [4 waves][16 q][72]
    unsigned short* sP = &sX[0][0];

    const int tid  = threadIdx.x;
    const int lane = tid & 63;
    const int wv   = tid >> 6;            // wave 0..3
    const int ln   = lane & 15;
    const int lg   = lane >> 4;           // 0..3

    const int h   = blockIdx.x & 7;
    const int wid = blockIdx.x >> 3;
    const int blw = wid >> 6;
    const int whr = (wid >> 3) & 7;
    const int wwc = wid & 7;
    const int tok_base = blw * 4096 + whr * 512 + wwc * 8;
    // token(i) = tok_base + (i>>3)*64 + (i&7)

    if (tid < 225) sPE[tid] = pe[tid];

    // ---- stage X (64 x 256 f32 -> bf16), coalesced ----
    #pragma unroll
    for (int it = 0; it < 16; ++it) {
        int g   = tid + (it << 8);
        int row = g >> 6;
        int f4  = g & 63;
        int tok = tok_base + ((row >> 3) << 6) + (row & 7);
        float4 v = *reinterpret_cast<const float4*>(x + (size_t)tok * 256 + f4 * 4);
        ushort4 u;
        u.x = f2bf(v.x); u.y = f2bf(v.y); u.z = f2bf(v.z); u.w = f2bf(v.w);
        *reinterpret_cast<ushort4*>(&sX[row][f4 << 2]) = u;
    }

    // ---- W^T chunk staging (96 n-rows x 64 k), transpose via scatter ----
    auto stage_w = [&](int kc) {
        #pragma unroll
        for (int it = 0; it < 8; ++it) {
            int g = tid + (it << 8);          // 0..2047
            int k = g >> 5;                   // 0..63
            int c = g & 31;
            if (c < 24) {
                int m  = c >> 3;              // 0..2 (q,k,v)
                int f4 = c & 7;               // 0..7
                float4 v = *reinterpret_cast<const float4*>(
                    w_qkv + (size_t)(kc * 64 + k) * 768 + m * 256 + h * 32 + f4 * 4);
                float vals[4] = {v.x, v.y, v.z, v.w};
                int n0 = m * 32 + f4 * 4;
                #pragma unroll
                for (int e0 = 0; e0 < 4; ++e0) {
                    int e = (e0 + lane) & 3;  // lane-rotated to spread banks
                    sW[n0 + e][k] = f2bf(vals[e]);
                }
            }
        }
    };

    stage_w(0);
    __syncthreads();

    // ---- QKV GEMM: wave wv = m-tile wv; 6 n-tiles (q0,q1,k0,k1,v0,v1) ----
    f32x4 acc[6];
    #pragma unroll
    for (int nt = 0; nt < 6; ++nt) acc[nt] = (f32x4)(0.f);

    for (int kc = 0; kc < 4; ++kc) {
        #pragma unroll
        for (int ks = 0; ks < 2; ++ks) {
            bf16x8 a = ldsFrag(&sX[wv * 16 + ln][kc * 64 + ks * 32 + lg * 8]);
            #pragma unroll
            for (int nt = 0; nt < 6; ++nt) {
                bf16x8 b = ldsFrag(&sW[nt * 16 + ln][ks * 32 + lg * 8]);
                acc[nt] = __builtin_amdgcn_mfma_f32_16x16x32_bf16(a, b, acc[nt], 0, 0, 0);
            }
        }
        if (kc < 3) {
            __syncthreads();
            stage_w(kc + 1);
            __syncthreads();
        }
    }

    // ---- epilogue: Q,K -> [tok][ch] (b16 scatter); V -> V^T packed b64 ----
    #pragma unroll
    for (int nt = 0; nt < 4; ++nt) {
        #pragma unroll
        for (int r = 0; r < 4; ++r) {
            int row = wv * 16 + lg * 4 + r;   // token row (C: row=4g+reg)
            unsigned short bv = f2bf(acc[nt][r]);
            if (nt < 2) sQ[row][nt * 16 + ln] = bv;
            else        sK[row][(nt - 2) * 16 + ln] = bv;
        }
    }
    #pragma unroll
    for (int nt = 4; nt < 6; ++nt) {
        ushort4 pv;
        pv.x = f2bf(acc[nt][0]); pv.y = f2bf(acc[nt][1]);
        pv.z = f2bf(acc[nt][2]); pv.w = f2bf(acc[nt][3]);
        *reinterpret_cast<ushort4*>(&sVT[(nt - 4) * 16 + ln][wv * 16 + lg * 4]) = pv;
    }
    __syncthreads();

    // ---- attention: wave wv handles queries 16wv..16wv+15 ----
    // S^T tiles: mfma(A=K(keys x ch), B=Q^T(ch x queries))
    const f32x4 zero = (f32x4)(0.f);
    bf16x8 qf = ldsFrag(&sQ[wv * 16 + ln][lg * 8]);   // B: n=query ln, k=ch 8lg..
    f32x4 st[4];
    #pragma unroll
    for (int mt = 0; mt < 4; ++mt) {
        bf16x8 kf = ldsFrag(&sK[mt * 16 + ln][lg * 8]); // A: row=key, k=ch
        st[mt] = __builtin_amdgcn_mfma_f32_16x16x32_bf16(kf, qf, zero, 0, 0, 0);
    }

    // softmax over keys for query q = 16wv + ln (lane&15); lane holds
    // keys j = 16mt + 4lg + r; groups l^16,l^32 complete the 64 keys.
    const int q  = wv * 16 + ln;
    const int qr = q >> 3, qc = q & 7;
    const float scale = 0.17677669529663687f;
    float sv[16];
    float mx = -3.0e38f;
    #pragma unroll
    for (int mt = 0; mt < 4; ++mt) {
        #pragma unroll
        for (int r = 0; r < 4; ++r) {
            int j  = mt * 16 + lg * 4 + r;
            int dy = (j >> 3) - qr + 7;
            int dx = (j & 7)  - qc + 7;
            float s = st[mt][r] * scale + sPE[dy * 15 + dx];
            sv[mt * 4 + r] = s;
            mx = fmaxf(mx, s);
        }
    }
    mx = fmaxf(mx, __shfl_xor(mx, 16));
    mx = fmaxf(mx, __shfl_xor(mx, 32));
    float sum = 0.f;
    #pragma unroll
    for (int i = 0; i < 16; ++i) { sv[i] = __expf(sv[i] - mx); sum += sv[i]; }
    sum += __shfl_xor(sum, 16);
    sum += __shfl_xor(sum, 32);
    const float inv = 1.0f / sum;

    // write P (bf16) row-contiguous: sP[wv][ln][key], packed 4 keys/write
    unsigned short* sPw = sP + wv * (16 * 72) + ln * 72;
    #pragma unroll
    for (int mt = 0; mt < 4; ++mt) {
        ushort4 pv;
        pv.x = f2bf(sv[mt * 4 + 0] * inv);
        pv.y = f2bf(sv[mt * 4 + 1] * inv);
        pv.z = f2bf(sv[mt * 4 + 2] * inv);
        pv.w = f2bf(sv[mt * 4 + 3] * inv);
        *reinterpret_cast<ushort4*>(sPw + mt * 16 + lg * 4) = pv;
    }

    // PV: O(16q x 32ch) = mfma(A=P(16x64), B=V(64x32)) over 2 k-steps
    f32x4 o[2] = {zero, zero};
    #pragma unroll
    for (int ks = 0; ks < 2; ++ks) {
        bf16x8 pf = ldsFrag(sPw + ks * 32 + lg * 8);
        #pragma unroll
        for (int nt = 0; nt < 2; ++nt) {
            bf16x8 vf = ldsFrag(&sVT[nt * 16 + ln][ks * 32 + lg * 8]);
            o[nt] = __builtin_amdgcn_mfma_f32_16x16x32_bf16(pf, vf, o[nt], 0, 0, 0);
        }
    }

    // write O fp32: row = query 16wv+4lg+r, col = h*32 + nt*16 + ln
    #pragma unroll
    for (int nt = 0; nt < 2; ++nt) {
        #pragma unroll
        for (int r = 0; r < 4; ++r) {
            int qi  = wv * 16 + lg * 4 + r;
            int tok = tok_base + ((qi >> 3) << 6) + (qi & 7);
            attn_out[(size_t)tok * 256 + h * 32 + nt * 16 + ln] = o[nt][r];
        }
    }
}

// =====================================================================
// Kernel 2: in-place projection out = A @ w_out + b_out (MFMA).
// grid = 1024 blocks x 64 rows, 256 threads = 4 waves; wave = m-tile.
// LDS 47,104 B -> 3 blocks/CU.
// =====================================================================
__global__ __launch_bounds__(256, 3)
void proj_kernel(float* __restrict__ io,
                 const float* __restrict__ w_out,
                 const float* __restrict__ b_out)
{
    __shared__ __align__(16) unsigned short sA[64][72];    // A chunk bf16
    __shared__ __align__(16) unsigned short sW2[256][72];  // W^T chunk (n-major)
    __shared__ float sB[256];

    const int tid  = threadIdx.x;
    const int lane = tid & 63;
    const int wv   = tid >> 6;
    const int ln   = lane & 15;
    const int lg   = lane >> 4;
    const size_t m0 = (size_t)blockIdx.x * 64;

    sB[tid] = b_out[tid];

    f32x4 acc[16];
    #pragma unroll
    for (int nt = 0; nt < 16; ++nt) acc[nt] = (f32x4)(0.f);

    for (int kc = 0; kc < 4; ++kc) {
        if (kc) __syncthreads();   // prev chunk reads done before restage

        // stage A rows (64 x 64 f32 -> bf16), coalesced
        #pragma unroll
        for (int it = 0; it < 4; ++it) {
            int g   = tid + (it << 8);
            int row = g >> 4;
            int f4  = g & 15;
            float4 v = *reinterpret_cast<const float4*>(
                io + (m0 + row) * 256 + kc * 64 + f4 * 4);
            ushort4 u;
            u.x = f2bf(v.x); u.y = f2bf(v.y); u.z = f2bf(v.z); u.w = f2bf(v.w);
            *reinterpret_cast<ushort4*>(&sA[row][f4 << 2]) = u;
        }
        // stage W^T chunk (256 n x 64 k): coalesced load, rotated scatter
        #pragma unroll
        for (int i = 0; i < 16; ++i) {
            int f4 = ln + 16 * (i & 3);                 // 0..63
            int kl = 16 * wv + lg + 4 * (i >> 2);       // 0..63 (wave-partition)
            float4 v = *reinterpret_cast<const float4*>(
                w_out + (size_t)(kc * 64 + kl) * 256 + f4 * 4);
            float vals[4] = {v.x, v.y, v.z, v.w};
            #pragma unroll
            for (int e0 = 0; e0 < 4; ++e0) {
                int e = (e0 + lane) & 3;
                sW2[f4 * 4 + e][kl] = f2bf(vals[e]);
            }
        }
        __syncthreads();

        #pragma unroll
        for (int ks = 0; ks < 2; ++ks) {
            bf16x8 a = ldsFrag(&sA[wv * 16 + ln][ks * 32 + lg * 8]);
            #pragma unroll
            for (int nt = 0; nt < 16; ++nt) {
                bf16x8 b = ldsFrag(&sW2[nt * 16 + ln][ks * 32 + lg * 8]);
                acc[nt] = __builtin_amdgcn_mfma_f32_16x16x32_bf16(a, b, acc[nt], 0, 0, 0);
            }
        }
    }

    // epilogue: bias + fp32 in-place write
    #pragma unroll
    for (int nt = 0; nt < 16; ++nt) {
        float bias = sB[nt * 16 + ln];
        #pragma unroll
        for (int r = 0; r < 4; ++r) {
            int row = wv * 16 + lg * 4 + r;
            io[(m0 + row) * 256 + nt * 16 + ln] = acc[nt][r] + bias;
        }
    }
}

extern "C" void kernel_launch(void* const* d_in, const int* in_sizes, int n_in,
                              void* d_out, int out_size, void* d_ws, size_t ws_size,
                              hipStream_t stream) {
    const float* x     = (const float*)d_in[0];  // (2,8,64,64,256) f32
    const float* w_qkv = (const float*)d_in[1];  // (256,768) f32
    const float* w_out = (const float*)d_in[2];  // (256,256) f32
    const float* b_out = (const float*)d_in[3];  // (256,) f32
    const float* pe    = (const float*)d_in[4];  // (15,15) f32
    (void)in_sizes; (void)n_in; (void)d_ws; (void)ws_size; (void)out_size;

    float* out = (float*)d_out;                  // (65536,256) f32

    winattn_kernel<<<dim3(8192), dim3(256), 0, stream>>>(x, w_qkv, pe, out);
    proj_kernel   <<<dim3(1024), dim3(256), 0, stream>>>(out, w_out, b_out);
}